// Round 3
// baseline (81.316 us; speedup 1.0000x reference)
//
#include <hip/hip_runtime.h>

#define N_BOXES 4194304
#define BCE_COEFF 0.2f
#define BLOCK 256
#define CHUNK_BOXES 1024                      // boxes staged per chunk
#define CHUNKS 4                              // chunks per block
#define BOXES_PER_BLOCK (CHUNK_BOXES * CHUNKS)
#define F4_PER_CHUNK (CHUNK_BOXES * 5 / 4)    // 1280 float4 per input per chunk

__global__ __launch_bounds__(BLOCK, 4) void eiou_bce_kernel(
        const float* __restrict__ preds,
        const float* __restrict__ target,
        float* __restrict__ out) {
    // 1024 boxes * 5 floats = 20 KB per input. 40 KB total LDS -> 4 blocks/CU.
    __shared__ float sp[CHUNK_BOXES * 5];
    __shared__ float st[CHUNK_BOXES * 5];
    float4* const sp4 = reinterpret_cast<float4*>(sp);
    float4* const st4 = reinterpret_cast<float4*>(st);

    const int t = threadIdx.x;
    const float4* const p4 = reinterpret_cast<const float4*>(preds);
    const float4* const t4 = reinterpret_cast<const float4*>(target);
    // block's first float4 index: blockIdx.x * 4096 boxes * 5/4
    const size_t blockF4 = (size_t)blockIdx.x * (BOXES_PER_BLOCK * 5 / 4);

    float acc = 0.0f;

    // ---- register-staged double buffer (T14): prologue load of chunk 0 ----
    float4 rp[5], rt[5];
#pragma unroll
    for (int k = 0; k < 5; ++k) {
        rp[k] = p4[blockF4 + k * BLOCK + t];
        rt[k] = t4[blockF4 + k * BLOCK + t];
    }

    for (int c = 0; ; ++c) {
        // Write staged registers to LDS (compiler inserts the vmcnt wait here,
        // i.e. AFTER the previous iteration's compute).
#pragma unroll
        for (int k = 0; k < 5; ++k) {
            sp4[k * BLOCK + t] = rp[k];
            st4[k * BLOCK + t] = rt[k];
        }
        __syncthreads();

        // Issue next chunk's global loads NOW; they stay in flight under the
        // compute below and are only waited on at the next LDS-write.
        if (c + 1 < CHUNKS) {
            const size_t nb = blockF4 + (size_t)(c + 1) * F4_PER_CHUNK;
#pragma unroll
            for (int k = 0; k < 5; ++k) {
                rp[k] = p4[nb + k * BLOCK + t];
                rt[k] = t4[nb + k * BLOCK + t];
            }
        }

        // ---- compute 4 boxes from LDS (stride-5 lanes -> conflict-free) ----
#pragma unroll
        for (int k = 0; k < 4; ++k) {
            const int b = t + k * BLOCK;
            const float* __restrict__ P = &sp[b * 5];
            const float* __restrict__ T = &st[b * 5];

            const float x = P[0];
            const float y = T[0];
            const float p0 = __fdividef(1.0f, 1.0f + __expf(-P[1]));
            const float p1 = __fdividef(1.0f, 1.0f + __expf(-P[2]));
            const float p2 = __fdividef(1.0f, 1.0f + __expf(-P[3]));
            const float p3 = __fdividef(1.0f, 1.0f + __expf(-P[4]));
            const float t0 = T[1], t1 = T[2], t2 = T[3], t3 = T[4];

            const float pred_area   = fabsf(p2 - p0) * fabsf(p3 - p1);
            const float target_area = (t2 - t0) * (t3 - t1);

            const float xp1 = fminf(p2, p0), xp2 = fmaxf(p2, p0);
            const float yp1 = fminf(p1, p3), yp2 = fmaxf(p1, p3);

            const float x1 = fmaxf(xp1, t0), x2 = fminf(xp2, t2);
            const float y1 = fmaxf(yp1, t1), y2 = fminf(yp2, t3);

            float ov = (x2 - x1) * (y2 - y1);
            ov = (ov < 0.0f) ? 0.0f : ov;

            const float x1c = fminf(xp1, t0), x2c = fmaxf(xp2, t2);
            const float y1c = fminf(yp1, t1), y2c = fmaxf(yp2, t3);

            const float cw = x2c - x1c, ch = y2c - y1c;
            const float w  = xp2 - xp1, wt = t2 - t0;
            const float h  = yp2 - yp1, ht = t3 - t1;

            const float iou = __fdividef(ov, target_area + pred_area - ov);

            const float cpx = (xp2 + xp1) * 0.5f, cpy = (yp2 + yp1) * 0.5f;
            const float ctx = (t2 + t0) * 0.5f,   cty = (t3 + t1) * 0.5f;
            const float diag = cw * cw + ch * ch;
            const float dx = cpx - ctx, dy = cpy - cty;

            const float center_part = __fdividef(dx * dx + dy * dy, diag);
            const float dwv = w - wt;
            const float width_part  = __fdividef(dwv * dwv, cw * cw);
            const float dhv = h - ht;
            const float height_part = __fdividef(dhv * dhv, ht * ht);

            const float eiou = 1.0f - (iou - (center_part + width_part + height_part));

            const float bce = fmaxf(x, 0.0f) - x * y
                            + __logf(1.0f + __expf(-fabsf(x)));

            acc += BCE_COEFF * bce + eiou;
        }

        if (c + 1 == CHUNKS) break;
        __syncthreads();   // protect LDS from next iteration's overwrite
    }

    // ---- wave-64 reduction ----
#pragma unroll
    for (int off = 32; off > 0; off >>= 1)
        acc += __shfl_down(acc, off);

    __syncthreads();              // all LDS compute reads done; reuse sp
    if ((t & 63) == 0) sp[t >> 6] = acc;
    __syncthreads();
    if (t == 0) {
        const float s = sp[0] + sp[1] + sp[2] + sp[3];
        atomicAdd(out, s * (1.0f / (float)N_BOXES));
    }
}

extern "C" void kernel_launch(void* const* d_in, const int* in_sizes, int n_in,
                              void* d_out, int out_size, void* d_ws, size_t ws_size,
                              hipStream_t stream) {
    const float* preds  = (const float*)d_in[0];
    const float* target = (const float*)d_in[1];
    float* out = (float*)d_out;

    // d_out is poisoned once before timing; zero it every call.
    hipMemsetAsync(out, 0, sizeof(float), stream);

    const int blocks = N_BOXES / BOXES_PER_BLOCK;   // 1024 blocks, 4/CU
    eiou_bce_kernel<<<blocks, BLOCK, 0, stream>>>(preds, target, out);
}

// Round 4
// 38.801 us; speedup vs baseline: 2.0957x; 2.0957x over previous
//
#include <hip/hip_runtime.h>

#define N_BOXES 4194304
#define BCE_COEFF 0.2f
#define BLOCK 256
#define CHUNK_BOXES 512                   // boxes per block
#define F4_PREDS (CHUNK_BOXES * 5 / 4)    // 640 float4 of preds per chunk
#define NSLOTS 256

// Stage one 512-box chunk (preds 10 KB + target 10 KB = 20 KB LDS) -> exactly
// 8 blocks/CU (160 KB LDS), 32 waves/CU. Overlap comes from inter-block TLP:
// no intra-block pipelining, no register staging (round-3 scratch disaster).
__global__ __launch_bounds__(BLOCK, 8) void eiou_bce_kernel(
        const float* __restrict__ preds,
        const float* __restrict__ target,
        float* __restrict__ slots) {
    __shared__ float s[CHUNK_BOXES * 5 * 2];          // 5120 floats = 20480 B
    float4* const s4 = reinterpret_cast<float4*>(s);

    const int t = threadIdx.x;
    const size_t f4Base = (size_t)blockIdx.x * (CHUNK_BOXES * 5 / 4);
    const float4* const p4 = reinterpret_cast<const float4*>(preds) + f4Base;
    const float4* const t4 = reinterpret_cast<const float4*>(target) + f4Base;

    // Coalesced staging: 1280 float4 total; idx<640 -> preds, else target.
    // Divergent POINTER (not control flow); only the k=2 wave straddles.
#pragma unroll
    for (int k = 0; k < 5; ++k) {
        const int idx = t + k * BLOCK;                // 0..1279
        const float4* src = (idx < F4_PREDS) ? (p4 + idx)
                                             : (t4 + (idx - F4_PREDS));
        s4[idx] = *src;
    }
    __syncthreads();

    float acc = 0.0f;
    // Thread handles boxes t and t+256. preds row at s[b*5], target row at
    // s[2560 + b*5]; lane stride 5 (odd) -> 2 lanes/bank, conflict-free.
#pragma unroll
    for (int k = 0; k < 2; ++k) {
        const int b = t + k * BLOCK;
        const float* __restrict__ P = &s[b * 5];
        const float* __restrict__ T = &s[CHUNK_BOXES * 5 + b * 5];

        const float x = P[0];
        const float y = T[0];
        const float p0 = __fdividef(1.0f, 1.0f + __expf(-P[1]));
        const float p1 = __fdividef(1.0f, 1.0f + __expf(-P[2]));
        const float p2 = __fdividef(1.0f, 1.0f + __expf(-P[3]));
        const float p3 = __fdividef(1.0f, 1.0f + __expf(-P[4]));
        const float t0 = T[1], t1 = T[2], t2 = T[3], t3 = T[4];

        // ---- EIoU (reference-exact dataflow, fast-math ops) ----
        const float pred_area   = fabsf(p2 - p0) * fabsf(p3 - p1);
        const float target_area = (t2 - t0) * (t3 - t1);

        const float xp1 = fminf(p2, p0), xp2 = fmaxf(p2, p0);
        const float yp1 = fminf(p1, p3), yp2 = fmaxf(p1, p3);

        const float x1 = fmaxf(xp1, t0), x2 = fminf(xp2, t2);
        const float y1 = fmaxf(yp1, t1), y2 = fminf(yp2, t3);

        float ov = (x2 - x1) * (y2 - y1);
        ov = (ov < 0.0f) ? 0.0f : ov;

        const float x1c = fminf(xp1, t0), x2c = fmaxf(xp2, t2);
        const float y1c = fminf(yp1, t1), y2c = fmaxf(yp2, t3);

        const float cw = x2c - x1c, ch = y2c - y1c;
        const float w  = xp2 - xp1, wt = t2 - t0;
        const float h  = yp2 - yp1, ht = t3 - t1;

        const float iou = __fdividef(ov, target_area + pred_area - ov);

        const float cpx = (xp2 + xp1) * 0.5f, cpy = (yp2 + yp1) * 0.5f;
        const float ctx = (t2 + t0) * 0.5f,   cty = (t3 + t1) * 0.5f;
        const float diag = cw * cw + ch * ch;
        const float dx = cpx - ctx, dy = cpy - cty;

        const float center_part = __fdividef(dx * dx + dy * dy, diag);
        const float dwv = w - wt;
        const float width_part  = __fdividef(dwv * dwv, cw * cw);
        const float dhv = h - ht;
        const float height_part = __fdividef(dhv * dhv, ht * ht);

        const float eiou = 1.0f - (iou - (center_part + width_part + height_part));

        const float bce = fmaxf(x, 0.0f) - x * y
                        + __logf(1.0f + __expf(-fabsf(x)));

        acc += BCE_COEFF * bce + eiou;
    }

    // ---- wave-64 reduction, then cross-wave via LDS ----
#pragma unroll
    for (int off = 32; off > 0; off >>= 1)
        acc += __shfl_down(acc, off);

    __syncthreads();                       // staging reads done; reuse s
    if ((t & 63) == 0) s[t >> 6] = acc;
    __syncthreads();
    if (t == 0) {
        const float bs = s[0] + s[1] + s[2] + s[3];
        // Spread contention over 256 slots (32 atomics/slot, parallel channels).
        atomicAdd(&slots[blockIdx.x & (NSLOTS - 1)], bs);
    }
}

__global__ __launch_bounds__(NSLOTS) void reduce_slots_kernel(
        const float* __restrict__ slots,
        float* __restrict__ out) {
    float v = slots[threadIdx.x];
#pragma unroll
    for (int off = 32; off > 0; off >>= 1)
        v += __shfl_down(v, off);

    __shared__ float ws[4];
    const int lane = threadIdx.x & 63;
    const int wid  = threadIdx.x >> 6;
    if (lane == 0) ws[wid] = v;
    __syncthreads();
    if (threadIdx.x == 0)
        out[0] = (ws[0] + ws[1] + ws[2] + ws[3]) * (1.0f / (float)N_BOXES);
}

extern "C" void kernel_launch(void* const* d_in, const int* in_sizes, int n_in,
                              void* d_out, int out_size, void* d_ws, size_t ws_size,
                              hipStream_t stream) {
    const float* preds  = (const float*)d_in[0];
    const float* target = (const float*)d_in[1];
    float* slots = (float*)d_ws;
    float* out   = (float*)d_out;

    // d_ws is poisoned once before timing; zero the slots every call.
    hipMemsetAsync(slots, 0, NSLOTS * sizeof(float), stream);

    const int blocks = N_BOXES / CHUNK_BOXES;        // 8192 blocks
    eiou_bce_kernel<<<blocks, BLOCK, 0, stream>>>(preds, target, slots);
    reduce_slots_kernel<<<1, NSLOTS, 0, stream>>>(slots, out);
}

// Round 5
// 34.958 us; speedup vs baseline: 2.3261x; 1.1099x over previous
//
#include <hip/hip_runtime.h>
#include <stdint.h>

#define N_BOXES 4194304
#define BCE_COEFF 0.2f
#define BLOCK 256
#define CHUNK 512                                // boxes per chunk
#define F4_PER_INPUT 640                         // 512*5/4 float4 per input
#define F4_PER_CHUNK 1280                        // both inputs
#define NBLOCKS 1024                             // exactly 4 blocks/CU, persistent
#define CHUNKS_PER_BLOCK (N_BOXES / CHUNK / NBLOCKS)   // 8

// Async global->LDS DMA, 16 B per lane. Dest must be linear (uniform base +
// lane*16) -- our staging layout is exactly that. No VGPR round-trip.
__device__ __forceinline__ void g2lds16(const float4* g, float4* l) {
    __builtin_amdgcn_global_load_lds(
        (const __attribute__((address_space(1))) void*)g,
        (__attribute__((address_space(3))) void*)l,
        16, 0, 0);
}

#define CFENCE() asm volatile("" ::: "memory")

__global__ __launch_bounds__(BLOCK) void eiou_main(
        const float* __restrict__ preds,
        const float* __restrict__ target,
        float* __restrict__ slots) {
    // 2 buffers x 1280 float4 = 40960 B -> 4 blocks/CU, 16 waves/CU.
    __shared__ float4 sbuf[2][F4_PER_CHUNK];

    const int t = threadIdx.x;
    const float4* const p4 = reinterpret_cast<const float4*>(preds);
    const float4* const t4 = reinterpret_cast<const float4*>(target);
    const int chunk0 = blockIdx.x * CHUNKS_PER_BLOCK;

    // ---- prologue: stage chunk0 -> buf0 (5 DMA ops/thread, 20 KB/block) ----
    {
        const size_t pb = (size_t)chunk0 * F4_PER_INPUT;
#pragma unroll
        for (int k = 0; k < 5; ++k) {
            const int idx = t + k * BLOCK;               // 0..1279
            const float4* src = (idx < F4_PER_INPUT) ? (p4 + pb + idx)
                                                     : (t4 + pb + (idx - F4_PER_INPUT));
            g2lds16(src, &sbuf[0][idx]);
        }
    }

    float acc = 0.0f;

    for (int c = 0; c < CHUNKS_PER_BLOCK; ++c) {
        const int buf = c & 1;

        if (c + 1 < CHUNKS_PER_BLOCK) {
            // Issue next chunk's DMA into the other buffer; stays in flight
            // across the barrier (counted vmcnt, never drained to 0 mid-loop).
            const size_t pb = (size_t)(chunk0 + c + 1) * F4_PER_INPUT;
#pragma unroll
            for (int k = 0; k < 5; ++k) {
                const int idx = t + k * BLOCK;
                const float4* src = (idx < F4_PER_INPUT) ? (p4 + pb + idx)
                                                         : (t4 + pb + (idx - F4_PER_INPUT));
                g2lds16(src, &sbuf[buf ^ 1][idx]);
            }
            // outstanding = 10 (5 current + 5 next); wait until current's 5 land.
            asm volatile("s_waitcnt vmcnt(5)" ::: "memory");
        } else {
            asm volatile("s_waitcnt vmcnt(0)" ::: "memory");
        }
        CFENCE();
        __builtin_amdgcn_s_barrier();     // all waves see buf fully staged
        CFENCE();

        const float* __restrict__ s = reinterpret_cast<const float*>(&sbuf[buf][0]);
#pragma unroll
        for (int k = 0; k < 2; ++k) {
            const int b = t + k * BLOCK;
            const float* __restrict__ P = &s[b * 5];
            const float* __restrict__ T = &s[CHUNK * 5 + b * 5];

            const float x = P[0];
            const float y = T[0];
            const float p0 = __fdividef(1.0f, 1.0f + __expf(-P[1]));
            const float p1 = __fdividef(1.0f, 1.0f + __expf(-P[2]));
            const float p2 = __fdividef(1.0f, 1.0f + __expf(-P[3]));
            const float p3 = __fdividef(1.0f, 1.0f + __expf(-P[4]));
            const float t0 = T[1], t1 = T[2], t2 = T[3], t3 = T[4];

            // ---- EIoU (reference-exact dataflow, fast-math ops) ----
            const float pred_area   = fabsf(p2 - p0) * fabsf(p3 - p1);
            const float target_area = (t2 - t0) * (t3 - t1);

            const float xp1 = fminf(p2, p0), xp2 = fmaxf(p2, p0);
            const float yp1 = fminf(p1, p3), yp2 = fmaxf(p1, p3);

            const float x1 = fmaxf(xp1, t0), x2 = fminf(xp2, t2);
            const float y1 = fmaxf(yp1, t1), y2 = fminf(yp2, t3);

            float ov = (x2 - x1) * (y2 - y1);
            ov = (ov < 0.0f) ? 0.0f : ov;

            const float x1c = fminf(xp1, t0), x2c = fmaxf(xp2, t2);
            const float y1c = fminf(yp1, t1), y2c = fmaxf(yp2, t3);

            const float cw = x2c - x1c, ch = y2c - y1c;
            const float w  = xp2 - xp1, wt = t2 - t0;
            const float h  = yp2 - yp1, ht = t3 - t1;

            const float iou = __fdividef(ov, target_area + pred_area - ov);

            const float cpx = (xp2 + xp1) * 0.5f, cpy = (yp2 + yp1) * 0.5f;
            const float ctx = (t2 + t0) * 0.5f,   cty = (t3 + t1) * 0.5f;
            const float diag = cw * cw + ch * ch;
            const float dx = cpx - ctx, dy = cpy - cty;

            const float center_part = __fdividef(dx * dx + dy * dy, diag);
            const float dwv = w - wt;
            const float width_part  = __fdividef(dwv * dwv, cw * cw);
            const float dhv = h - ht;
            const float height_part = __fdividef(dhv * dhv, ht * ht);

            const float eiou = 1.0f - (iou - (center_part + width_part + height_part));

            const float bce = fmaxf(x, 0.0f) - x * y
                            + __logf(1.0f + __expf(-fabsf(x)));

            acc += BCE_COEFF * bce + eiou;
        }

        CFENCE();
        __builtin_amdgcn_s_barrier();     // reads of buf done before re-staging it
        CFENCE();
    }

    // ---- block reduction (no atomics, no memset needed) ----
#pragma unroll
    for (int off = 32; off > 0; off >>= 1)
        acc += __shfl_down(acc, off);

    float* sfl = reinterpret_cast<float*>(&sbuf[0][0]);   // safe: loop done
    if ((t & 63) == 0) sfl[t >> 6] = acc;
    __syncthreads();
    if (t == 0) slots[blockIdx.x] = (sfl[0] + sfl[1]) + (sfl[2] + sfl[3]);
}

__global__ __launch_bounds__(256) void reduce_slots_kernel(
        const float* __restrict__ slots,
        float* __restrict__ out) {
    const float4 v4 = reinterpret_cast<const float4*>(slots)[threadIdx.x]; // 1024 floats
    float v = (v4.x + v4.y) + (v4.z + v4.w);
#pragma unroll
    for (int off = 32; off > 0; off >>= 1)
        v += __shfl_down(v, off);

    __shared__ float ws[4];
    const int lane = threadIdx.x & 63;
    const int wid  = threadIdx.x >> 6;
    if (lane == 0) ws[wid] = v;
    __syncthreads();
    if (threadIdx.x == 0)
        out[0] = ((ws[0] + ws[1]) + (ws[2] + ws[3])) * (1.0f / (float)N_BOXES);
}

extern "C" void kernel_launch(void* const* d_in, const int* in_sizes, int n_in,
                              void* d_out, int out_size, void* d_ws, size_t ws_size,
                              hipStream_t stream) {
    const float* preds  = (const float*)d_in[0];
    const float* target = (const float*)d_in[1];
    float* slots = (float*)d_ws;      // 1024 floats; fully rewritten every call
    float* out   = (float*)d_out;

    eiou_main<<<NBLOCKS, BLOCK, 0, stream>>>(preds, target, slots);
    reduce_slots_kernel<<<1, 256, 0, stream>>>(slots, out);
}

// Round 6
// 34.192 us; speedup vs baseline: 2.3782x; 1.0224x over previous
//
#include <hip/hip_runtime.h>

#define N_BOXES 4194304
#define BCE_COEFF 0.2f
#define BLOCK 256
#define WAVES 4
#define WCHUNK 128                           // boxes per wave-chunk
#define F4_IN (WCHUNK * 5 / 4)               // 160 float4 per input per chunk
#define F4_TOT (F4_IN * 2)                   // 320 float4 (preds + target)
#define NBLOCKS 1024                         // persistent, 4 blocks/CU by LDS
#define BOXES_PER_WAVE (N_BOXES / NBLOCKS / WAVES)   // 1024
#define ROUNDS (BOXES_PER_WAVE / WCHUNK)             // 8

// Async global->LDS DMA, 16 B/lane. HW semantics: wave-uniform LDS base +
// lane*16; our per-lane dest pointer equals exactly that (linear layout).
__device__ __forceinline__ void g2lds16(const float4* g, float4* l) {
    __builtin_amdgcn_global_load_lds(
        (const __attribute__((address_space(1))) void*)g,
        (__attribute__((address_space(3))) void*)l,
        16, 0, 0);
}

__global__ __launch_bounds__(BLOCK) void eiou_main(
        const float* __restrict__ preds,
        const float* __restrict__ target,
        float* __restrict__ slots) {
    // Wave-private double buffers: 4 waves x 2 bufs x 320 float4 = 40960 B.
    __shared__ float4 sbuf[WAVES][2][F4_TOT];

    const int t    = threadIdx.x;
    const int lane = t & 63;
    const int w    = t >> 6;
    const float4* const p4 = reinterpret_cast<const float4*>(preds);
    const float4* const t4 = reinterpret_cast<const float4*>(target);

    // Wave's first float4 index (per input): block*5120 + w*1280.
    const size_t wbase = (size_t)blockIdx.x * (N_BOXES / NBLOCKS * 5 / 4)
                       + (size_t)w * (BOXES_PER_WAVE * 5 / 4);

    // ---- stage one 128-box wave-chunk: 5 DMA instrs, 5 KB ----
    auto stage = [&](int c, int b) {
        const size_t fb = wbase + (size_t)c * F4_IN;
#pragma unroll
        for (int k = 0; k < 5; ++k) {
            const int q = k * 64 + lane;                 // 0..319
            const float4* src = (q < F4_IN) ? (p4 + fb + q)
                                            : (t4 + fb + (q - F4_IN));
            g2lds16(src, &sbuf[w][b][q]);
        }
    };

    stage(0, 0);                     // prologue
    float acc = 0.0f;

    // ---- barrier-free per-wave pipeline ----
    for (int c = 0; c < ROUNDS; ++c) {
        const int b = c & 1;
        if (c + 1 < ROUNDS) {
            // my ds_reads of buf b^1 (chunk c-1) fully retired before the DMA
            // engine may overwrite that buffer:
            asm volatile("s_waitcnt lgkmcnt(0)" ::: "memory");
            stage(c + 1, b ^ 1);                         // in flight under compute
            asm volatile("s_waitcnt vmcnt(5)" ::: "memory");  // chunk c landed
        } else {
            asm volatile("s_waitcnt vmcnt(0)" ::: "memory");
        }

        const float* __restrict__ s = reinterpret_cast<const float*>(&sbuf[w][b][0]);
#pragma unroll
        for (int j = 0; j < 2; ++j) {
            const int box = lane + j * 64;               // 0..127
            const float* __restrict__ P = s + box * 5;           // preds row
            const float* __restrict__ T = s + WCHUNK * 5 + box * 5; // target row

            const float x = P[0];
            const float y = T[0];
            const float p0 = __fdividef(1.0f, 1.0f + __expf(-P[1]));
            const float p1 = __fdividef(1.0f, 1.0f + __expf(-P[2]));
            const float p2 = __fdividef(1.0f, 1.0f + __expf(-P[3]));
            const float p3 = __fdividef(1.0f, 1.0f + __expf(-P[4]));
            const float t0 = T[1], t1 = T[2], t2 = T[3], t3 = T[4];

            // ---- EIoU (reference-exact dataflow, fast-math ops) ----
            const float pred_area   = fabsf(p2 - p0) * fabsf(p3 - p1);
            const float target_area = (t2 - t0) * (t3 - t1);

            const float xp1 = fminf(p2, p0), xp2 = fmaxf(p2, p0);
            const float yp1 = fminf(p1, p3), yp2 = fmaxf(p1, p3);

            const float x1 = fmaxf(xp1, t0), x2 = fminf(xp2, t2);
            const float y1 = fmaxf(yp1, t1), y2 = fminf(yp2, t3);

            float ov = (x2 - x1) * (y2 - y1);
            ov = (ov < 0.0f) ? 0.0f : ov;

            const float x1c = fminf(xp1, t0), x2c = fmaxf(xp2, t2);
            const float y1c = fminf(yp1, t1), y2c = fmaxf(yp2, t3);

            const float cw = x2c - x1c, ch = y2c - y1c;
            const float w2 = xp2 - xp1, wt = t2 - t0;
            const float h  = yp2 - yp1, ht = t3 - t1;

            const float iou = __fdividef(ov, target_area + pred_area - ov);

            const float cpx = (xp2 + xp1) * 0.5f, cpy = (yp2 + yp1) * 0.5f;
            const float ctx = (t2 + t0) * 0.5f,   cty = (t3 + t1) * 0.5f;
            const float diag = cw * cw + ch * ch;
            const float dx = cpx - ctx, dy = cpy - cty;

            const float center_part = __fdividef(dx * dx + dy * dy, diag);
            const float dwv = w2 - wt;
            const float width_part  = __fdividef(dwv * dwv, cw * cw);
            const float dhv = h - ht;
            const float height_part = __fdividef(dhv * dhv, ht * ht);

            const float eiou = 1.0f - (iou - (center_part + width_part + height_part));

            const float bce = fmaxf(x, 0.0f) - x * y
                            + __logf(1.0f + __expf(-fabsf(x)));

            acc += BCE_COEFF * bce + eiou;
        }
    }

    // ---- block reduction ----
#pragma unroll
    for (int off = 32; off > 0; off >>= 1)
        acc += __shfl_down(acc, off);

    __syncthreads();                 // everyone done with their LDS region
    float* sf = reinterpret_cast<float*>(&sbuf[0][0][0]);
    if (lane == 0) sf[w] = acc;
    __syncthreads();
    if (t == 0) slots[blockIdx.x] = (sf[0] + sf[1]) + (sf[2] + sf[3]);
}

__global__ __launch_bounds__(256) void reduce_slots_kernel(
        const float* __restrict__ slots,
        float* __restrict__ out) {
    const float4 v4 = reinterpret_cast<const float4*>(slots)[threadIdx.x]; // 1024 floats
    float v = (v4.x + v4.y) + (v4.z + v4.w);
#pragma unroll
    for (int off = 32; off > 0; off >>= 1)
        v += __shfl_down(v, off);

    __shared__ float ws[4];
    const int lane = threadIdx.x & 63;
    const int wid  = threadIdx.x >> 6;
    if (lane == 0) ws[wid] = v;
    __syncthreads();
    if (threadIdx.x == 0)
        out[0] = ((ws[0] + ws[1]) + (ws[2] + ws[3])) * (1.0f / (float)N_BOXES);
}

extern "C" void kernel_launch(void* const* d_in, const int* in_sizes, int n_in,
                              void* d_out, int out_size, void* d_ws, size_t ws_size,
                              hipStream_t stream) {
    const float* preds  = (const float*)d_in[0];
    const float* target = (const float*)d_in[1];
    float* slots = (float*)d_ws;      // 1024 floats; fully rewritten every call
    float* out   = (float*)d_out;

    eiou_main<<<NBLOCKS, BLOCK, 0, stream>>>(preds, target, slots);
    reduce_slots_kernel<<<1, 256, 0, stream>>>(slots, out);
}